// Round 17
// baseline (182.512 us; speedup 1.0000x reference)
//
#include <hip/hip_runtime.h>
#include <hip/hip_bf16.h>

// Problem constants
#define N_ROWS 8192
#define D_DIM  1024
#define HALF_N 4096
#define N_TILES 2080             // 64*65/2 upper-triangular 128x128 tile pairs
#define N_RED  8                 // parallel loss-reduction blocks
constexpr float INV_T = 1.0f / 0.07f;   // 14.2857143 — also the fixed softmax max M

typedef __attribute__((ext_vector_type(4))) float f32x4;
typedef __attribute__((ext_vector_type(4))) int v4i;
typedef __attribute__((ext_vector_type(8))) int v8i;

// async global->LDS, 16B/lane. LDS dest is wave-uniform base + lane*16.
__device__ __forceinline__ void async_ld16(const void* g, void* lds) {
    __builtin_amdgcn_global_load_lds(
        (const __attribute__((address_space(1))) void*)g,
        (__attribute__((address_space(3))) void*)lds,
        16, 0, 0);
}

// pack 4 floats -> 4 OCP e4m3 bytes in one dword
__device__ __forceinline__ unsigned int pk_fp8x4(float a, float b, float c, float d) {
    int v = __builtin_amdgcn_cvt_pk_fp8_f32(a, b, 0, false);   // bytes 0,1
    v = __builtin_amdgcn_cvt_pk_fp8_f32(c, d, v, true);        // bytes 2,3
    return (unsigned int)v;
}

// ---------------------------------------------------------------------------
// Kernel 1: row norms + fp8 e4m3 normalized copy + zeroing of row_sum and the
// handshake cells (done_cnt, fin_cnt, loss_acc). One wave per row.
__global__ __launch_bounds__(256) void norm_kernel(const float* __restrict__ feat,
                                                   unsigned char* __restrict__ fn8,
                                                   float* __restrict__ row_sum,
                                                   unsigned int* __restrict__ done_cnt,
                                                   unsigned int* __restrict__ fin_cnt,
                                                   float* __restrict__ loss_acc) {
    const int w = threadIdx.x >> 6, lane = threadIdx.x & 63;
    const int row = blockIdx.x * 4 + w;
    if (blockIdx.x == 0 && threadIdx.x == 0) {
        *done_cnt = 0u;
        *fin_cnt = 0u;
        *loss_acc = 0.f;
    }
    const float4* src = (const float4*)(feat + (size_t)row * D_DIM);
    float4 v[4];
    float ss = 0.f;
#pragma unroll
    for (int t = 0; t < 4; ++t) {
        v[t] = src[lane + 64 * t];
        ss += v[t].x * v[t].x + v[t].y * v[t].y + v[t].z * v[t].z + v[t].w * v[t].w;
    }
#pragma unroll
    for (int off = 32; off; off >>= 1) ss += __shfl_xor(ss, off);
    float nrm = fmaxf(sqrtf(ss), 1e-8f);
    if (lane == 0) row_sum[row] = 0.f;
    const float inv = 1.0f / nrm;
    unsigned int* dst = (unsigned int*)(fn8 + (size_t)row * D_DIM);
#pragma unroll
    for (int t = 0; t < 4; ++t)
        dst[lane + 64 * t] = pk_fp8x4(v[t].x * inv, v[t].y * inv, v[t].z * inv, v[t].w * inv);
}

// ---------------------------------------------------------------------------
// Kernel 2: SYMMETRIC triangular sim GEMM, MX-SCALED FP8 K=128 + fixed-max
// exp acc + s_target extraction + fence-free fused loss tail (8-way).
// r17 change: mfma_scale_f32_16x16x128_f8f6f4 with unit scales (E8M0=0x7F):
// one MFMA per fragment pair covers K=128 at 2x the non-scaled fp8 rate
// (m148: 1628 TF). BK=128 B -> 8 windows (was 16): barrier-drain events and
// MFMA cycles both halve; staged bytes and LDS-read counts unchanged.
// Correctness shields: A and B fragments use the SAME (row->lane, byte->k)
// map, so the instruction's internal k-order cancels (r16-proven argument);
// C/D layout is shape-determined (same as all 16x16 MFMAs) -> epilogue
// untouched. LDS: row stride 128 B = exact bank wrap; physical unit =
// logical ^ (row&7) puts 2 lanes per 4-bank group per quarter-wave ->
// conflict-free; read offsets kt-invariant (2 hoisted bases).
// Frozen lessons: no dbuf (r7), no forced occupancy (r4), no device fences
// (r11), batched tail loads (r13), 8-way tail (r15), k-permuted reads (r16).
__global__ __launch_bounds__(256) void simgemm_kernel(const unsigned char* __restrict__ fn8,
                                                      float* __restrict__ row_sum,
                                                      float* __restrict__ s_target,
                                                      unsigned int* __restrict__ done_cnt,
                                                      unsigned int* __restrict__ fin_cnt,
                                                      float* __restrict__ loss_acc,
                                                      float* __restrict__ out) {
    __shared__ __align__(16) unsigned char As[128 * 128];   // 16 KiB
    __shared__ __align__(16) unsigned char Bs[128 * 128];   // 16 KiB
    // triangular decode: t -> (I,J), I<=J
    const int t = blockIdx.x;
    int a = (int)((sqrtf(8.f * (float)t + 1.f) - 1.f) * 0.5f);
    while ((a + 1) * (a + 2) / 2 <= t) ++a;
    while (a * (a + 1) / 2 > t) --a;
    const int I = t - a * (a + 1) / 2;   // row-tile index (<= J)
    const int J = a;                     // col-tile index
    const int r0 = I * 128, c0 = J * 128;
    const bool isdiag = (I == J);
    const bool haspair = (J == I + 32);  // contains sim[i, i+4096] for rows in I

    const int tid = threadIdx.x;
    const int w = tid >> 6, lane = tid & 63;
    const int q = lane >> 4, c16 = lane & 15;
    const int wr = (w >> 1) * 64;  // wave's row base within tile
    const int wc = (w & 1) * 64;   // wave's col base within tile
    // staging: wave w stages rows [w*32, w*32+32) as 4 chunks of 8 rows.
    // Lane l -> chunk row l>>3, physical unit l&7; fetches logical unit
    // (l&7) ^ (row&7) (rotate-within-row swizzle; row&7 == l>>3 here).
    const int srow = lane >> 3;                          // row within chunk
    const int skoff = ((lane & 7) ^ srow) * 16;          // swizzled unit byte offset
    // fragment read byte offsets (kt/i-invariant): row R has R&7 == c16&7;
    // logical units 2q, 2q+1 sit at physical (2q+h) ^ (c16&7).
    const int s7 = c16 & 7;
    const int lfo0 = c16 * 128 + (((2 * q + 0) ^ s7) * 16);
    const int lfo1 = c16 * 128 + (((2 * q + 1) ^ s7) * 16);

    const unsigned char* pa = fn8 + (size_t)(r0 + w * 32 + srow) * D_DIM + skoff;
    const unsigned char* pb = fn8 + (size_t)(c0 + w * 32 + srow) * D_DIM + skoff;

    f32x4 acc[4][4];
#pragma unroll
    for (int i = 0; i < 4; ++i)
#pragma unroll
        for (int j = 0; j < 4; ++j) acc[i][j] = (f32x4){0.f, 0.f, 0.f, 0.f};

    for (int kt = 0; kt < 8; ++kt) {
        __syncthreads();  // previous window's reads done before overwrite
#pragma unroll
        for (int c = 0; c < 4; ++c) {
            async_ld16(pa + c * 8 * D_DIM, (void*)&As[(w * 4 + c) * 1024]);
            async_ld16(pb + c * 8 * D_DIM, (void*)&Bs[(w * 4 + c) * 1024]);
        }
        pa += 128; pb += 128;
        __syncthreads();  // drains vmcnt(0): staging visible

        v8i af[4], bf[4];
#pragma unroll
        for (int i = 0; i < 4; ++i) {
            v4i lo = *(const v4i*)&As[(wr + i * 16) * 128 + lfo0];
            v4i hi = *(const v4i*)&As[(wr + i * 16) * 128 + lfo1];
            af[i] = __builtin_shufflevector(lo, hi, 0, 1, 2, 3, 4, 5, 6, 7);
        }
#pragma unroll
        for (int j = 0; j < 4; ++j) {
            v4i lo = *(const v4i*)&Bs[(wc + j * 16) * 128 + lfo0];
            v4i hi = *(const v4i*)&Bs[(wc + j * 16) * 128 + lfo1];
            bf[j] = __builtin_shufflevector(lo, hi, 0, 1, 2, 3, 4, 5, 6, 7);
        }
#pragma unroll
        for (int i = 0; i < 4; ++i)
#pragma unroll
            for (int j = 0; j < 4; ++j)
                acc[i][j] = __builtin_amdgcn_mfma_scale_f32_16x16x128_f8f6f4(
                    af[i], bf[j], acc[i][j],
                    0, 0,                      // cbsz=0 (A=fp8 e4m3), blgp=0 (B=fp8 e4m3)
                    0, 0x7f7f7f7f,             // A scale: opsel 0, E8M0=127 -> 1.0
                    0, 0x7f7f7f7f);            // B scale: opsel 0, E8M0=127 -> 1.0
    }

    // epilogue: e = exp(sim - M); rows-in-I sums + (I<J) cols-in-J sums.
    float cs[4] = {0.f, 0.f, 0.f, 0.f};   // per-j column partial sums
#pragma unroll
    for (int i = 0; i < 4; ++i) {
        const int growb = r0 + wr + i * 16 + q * 4;
#pragma unroll
        for (int r = 0; r < 4; ++r) {
            const int grow = growb + r;
            float s = 0.f;
#pragma unroll
            for (int j = 0; j < 4; ++j) {
                const int gcol = c0 + wc + j * 16 + c16;
                float sim = acc[i][j][r] * INV_T;
                float e = __expf(sim - INV_T);
                if (isdiag && grow == gcol) e = 0.f;   // diagonal mask
                if (haspair && gcol == grow + HALF_N) {
                    __hip_atomic_store(&s_target[grow], sim, __ATOMIC_RELAXED,
                                       __HIP_MEMORY_SCOPE_AGENT);
                    __hip_atomic_store(&s_target[gcol], sim, __ATOMIC_RELAXED,
                                       __HIP_MEMORY_SCOPE_AGENT);
                }
                s += e;
                cs[j] += e;
            }
            // row path: reduce over the 16 col-lanes of the quad
            s += __shfl_xor(s, 1);
            s += __shfl_xor(s, 2);
            s += __shfl_xor(s, 4);
            s += __shfl_xor(s, 8);
            if (c16 == 0) atomicAdd(&row_sum[grow], s);
        }
    }
    if (!isdiag) {
        // col path: reduce each cs[j] across the 4 quads, one atomic/column
#pragma unroll
        for (int j = 0; j < 4; ++j) {
            float s = cs[j];
            s += __shfl_xor(s, 16);
            s += __shfl_xor(s, 32);
            if (q == 0) atomicAdd(&row_sum[c0 + wc + j * 16 + c16], s);
        }
    }

    // ---- fence-free fused loss tail, 8-way parallel ----
    __syncthreads();   // all waves' vmem drained (compiler emits vmcnt(0) here)
    __shared__ unsigned int my_ord;
    if (tid == 0)
        my_ord = __hip_atomic_fetch_add(done_cnt, 1u, __ATOMIC_RELAXED,
                                        __HIP_MEMORY_SCOPE_AGENT);
    __syncthreads();
    const unsigned int ord = my_ord;
    if (ord >= N_TILES - N_RED) {
        // wait until ALL 2080 blocks have signalled (their sums are in).
        if (tid == 0) {
            while (__hip_atomic_load(done_cnt, __ATOMIC_RELAXED,
                                     __HIP_MEMORY_SCOPE_AGENT) < N_TILES)
                __builtin_amdgcn_s_sleep(1);
        }
        __syncthreads();
        const int slice = (int)(ord - (N_TILES - N_RED));   // 0..7
        const int base_row = slice * (N_ROWS / N_RED) + tid * 4;
        float rv[4], sv[4];
#pragma unroll
        for (int u = 0; u < 4; ++u) {
            rv[u] = __hip_atomic_load(&row_sum[base_row + u], __ATOMIC_RELAXED,
                                      __HIP_MEMORY_SCOPE_AGENT);
            sv[u] = __hip_atomic_load(&s_target[base_row + u], __ATOMIC_RELAXED,
                                      __HIP_MEMORY_SCOPE_AGENT);
        }
        float local = 0.f;
#pragma unroll
        for (int u = 0; u < 4; ++u)
            local += __logf(rv[u]) - sv[u];
#pragma unroll
        for (int off = 32; off; off >>= 1) local += __shfl_xor(local, off);
        __shared__ float part[4];
        if ((tid & 63) == 0) part[tid >> 6] = local;
        __syncthreads();
        if (tid == 0) {
            float bsum = part[0] + part[1] + part[2] + part[3];
            __hip_atomic_fetch_add(loss_acc, bsum, __ATOMIC_RELAXED,
                                   __HIP_MEMORY_SCOPE_AGENT);
            unsigned int f = __hip_atomic_fetch_add(fin_cnt, 1u, __ATOMIC_ACQ_REL,
                                                    __HIP_MEMORY_SCOPE_AGENT);
            if (f == N_RED - 1) {
                float accv = __hip_atomic_load(loss_acc, __ATOMIC_RELAXED,
                                               __HIP_MEMORY_SCOPE_AGENT);
                out[0] = INV_T + accv * (1.0f / N_ROWS);
            }
        }
    }
}

// ---------------------------------------------------------------------------
extern "C" void kernel_launch(void* const* d_in, const int* in_sizes, int n_in,
                              void* d_out, int out_size, void* d_ws, size_t ws_size,
                              hipStream_t stream) {
    const float* feat = (const float*)d_in[0];
    float* out = (float*)d_out;
    char* ws = (char*)d_ws;

    unsigned char* fn8 = (unsigned char*)ws;                  // 8192*1024 fp8 = 8 MiB
    size_t off = (size_t)N_ROWS * D_DIM;
    float* row_sum = (float*)(ws + off);   off += N_ROWS * sizeof(float);
    float* s_target = (float*)(ws + off);  off += N_ROWS * sizeof(float);
    unsigned int* done_cnt = (unsigned int*)(ws + off);  off += sizeof(unsigned int);
    unsigned int* fin_cnt = (unsigned int*)(ws + off);   off += sizeof(unsigned int);
    float* loss_acc = (float*)(ws + off);

    norm_kernel<<<N_ROWS / 4, 256, 0, stream>>>(feat, fn8, row_sum, done_cnt, fin_cnt, loss_acc);
    simgemm_kernel<<<N_TILES, 256, 0, stream>>>(fn8, row_sum, s_target, done_cnt, fin_cnt, loss_acc, out);
}

// Round 18
// 141.711 us; speedup vs baseline: 1.2879x; 1.2879x over previous
//
#include <hip/hip_runtime.h>
#include <hip/hip_bf16.h>

// Problem constants
#define N_ROWS 8192
#define D_DIM  1024
#define HALF_N 4096
#define N_TILES 2080             // 64*65/2 upper-triangular 128x128 tile pairs
#define N_RED  8                 // parallel loss-reduction blocks
constexpr float INV_T = 1.0f / 0.07f;   // 14.2857143 — also the fixed softmax max M

typedef __attribute__((ext_vector_type(4))) float f32x4;
typedef __attribute__((ext_vector_type(2))) long long2_;   // 16B = one ds_read_b128

// async global->LDS, 16B/lane. LDS dest is wave-uniform base + lane*16.
__device__ __forceinline__ void async_ld16(const void* g, void* lds) {
    __builtin_amdgcn_global_load_lds(
        (const __attribute__((address_space(1))) void*)g,
        (__attribute__((address_space(3))) void*)lds,
        16, 0, 0);
}

// pack 4 floats -> 4 OCP e4m3 bytes in one dword
__device__ __forceinline__ unsigned int pk_fp8x4(float a, float b, float c, float d) {
    int v = __builtin_amdgcn_cvt_pk_fp8_f32(a, b, 0, false);   // bytes 0,1
    v = __builtin_amdgcn_cvt_pk_fp8_f32(c, d, v, true);        // bytes 2,3
    return (unsigned int)v;
}

// ---------------------------------------------------------------------------
// Kernel 1: row norms + fp8 e4m3 normalized copy + zeroing of row_sum and the
// handshake cells (done_cnt, fin_cnt, loss_acc). One wave per row.
__global__ __launch_bounds__(256) void norm_kernel(const float* __restrict__ feat,
                                                   unsigned char* __restrict__ fn8,
                                                   float* __restrict__ row_sum,
                                                   unsigned int* __restrict__ done_cnt,
                                                   unsigned int* __restrict__ fin_cnt,
                                                   float* __restrict__ loss_acc) {
    const int w = threadIdx.x >> 6, lane = threadIdx.x & 63;
    const int row = blockIdx.x * 4 + w;
    if (blockIdx.x == 0 && threadIdx.x == 0) {
        *done_cnt = 0u;
        *fin_cnt = 0u;
        *loss_acc = 0.f;
    }
    const float4* src = (const float4*)(feat + (size_t)row * D_DIM);
    float4 v[4];
    float ss = 0.f;
#pragma unroll
    for (int t = 0; t < 4; ++t) {
        v[t] = src[lane + 64 * t];
        ss += v[t].x * v[t].x + v[t].y * v[t].y + v[t].z * v[t].z + v[t].w * v[t].w;
    }
#pragma unroll
    for (int off = 32; off; off >>= 1) ss += __shfl_xor(ss, off);
    float nrm = fmaxf(sqrtf(ss), 1e-8f);
    if (lane == 0) row_sum[row] = 0.f;
    const float inv = 1.0f / nrm;
    unsigned int* dst = (unsigned int*)(fn8 + (size_t)row * D_DIM);
#pragma unroll
    for (int t = 0; t < 4; ++t)
        dst[lane + 64 * t] = pk_fp8x4(v[t].x * inv, v[t].y * inv, v[t].z * inv, v[t].w * inv);
}

// ---------------------------------------------------------------------------
// Kernel 2: SYMMETRIC triangular sim GEMM in FP8 (e4m3) + fixed-max exp acc
// + s_target extraction + fence-free fused loss tail (8-way parallel).
// FINAL (r16) configuration — the measured optimum of this design space:
//  * fp8 e4m3 operands (r12: halves staged bytes vs bf16, same MFMA count)
//  * symmetry: only 2080 upper-triangular tile pairs, col-sums reused (r8)
//  * BK=64 B, 16 windows, 2 barriers/window (r7/r10: all pipelining
//    embellishments on this structure regressed)
//  * rotate-within-row staging swizzle + K-PERMUTED b128 fragment reads
//    (r6/r16): MFMA1 lane-q k := [16q,16q+8), MFMA2 := [16q+8,16q+16) — dot
//    products are permutation-invariant when A and B share the permutation,
//    so each lane reads ONE contiguous ds_read_b128; SQ_LDS_BANK_CONFLICT=0
//  * natural register allocation, 84 VGPR (r4: forcing occupancy spills;
//    r17: MX K=128 fragments cost 256 VGPR and 1 wave/SIMD)
//  * fence-free done-counter tail, batched loads, 8-way parallel reduction
//    (r11: device fences = L2 storm; r13: unbatched loads serialize)
// Measured: simgemm 77.3 us (903 TF eff ~ 91% of the m145 fp8 plateau),
// total 142.4 us.
__global__ __launch_bounds__(256) void simgemm_kernel(const unsigned char* __restrict__ fn8,
                                                      float* __restrict__ row_sum,
                                                      float* __restrict__ s_target,
                                                      unsigned int* __restrict__ done_cnt,
                                                      unsigned int* __restrict__ fin_cnt,
                                                      float* __restrict__ loss_acc,
                                                      float* __restrict__ out) {
    __shared__ __align__(16) unsigned char As[128 * 64];   // 8 KiB
    __shared__ __align__(16) unsigned char Bs[128 * 64];   // 8 KiB
    // triangular decode: t -> (I,J), I<=J
    const int t = blockIdx.x;
    int a = (int)((sqrtf(8.f * (float)t + 1.f) - 1.f) * 0.5f);
    while ((a + 1) * (a + 2) / 2 <= t) ++a;
    while (a * (a + 1) / 2 > t) --a;
    const int I = t - a * (a + 1) / 2;   // row-tile index (<= J)
    const int J = a;                     // col-tile index
    const int r0 = I * 128, c0 = J * 128;
    const bool isdiag = (I == J);
    const bool haspair = (J == I + 32);  // contains sim[i, i+4096] for rows in I

    const int tid = threadIdx.x;
    const int w = tid >> 6, lane = tid & 63;
    const int q = lane >> 4, c16 = lane & 15;
    const int wr = (w >> 1) * 64;  // wave's row base within tile
    const int wc = (w & 1) * 64;   // wave's col base within tile
    const int wr4 = (w >> 1) * 4;  // wave's A chunk base (16-row chunks)
    const int wc4 = (w & 1) * 4;   // wave's B chunk base
    // staging: wave w stages chunks 2w, 2w+1 (rows w*32 .. w*32+31).
    const int srow = lane >> 2;                               // row within chunk
    const int skoff = ((lane & 3) ^ ((srow >> 1) & 3)) * 16;  // swizzled unit byte offset
    // fragment read byte offset within a chunk (kt-invariant): logical unit q
    // of row c16 sits at physical unit q ^ f(c16), f(r) = (r>>1)&3.
    const int lfo = c16 * 64 + ((q ^ ((c16 >> 1) & 3)) * 16);

    const unsigned char* pa0 = fn8 + (size_t)(r0 + w * 32 + srow) * D_DIM + skoff;
    const unsigned char* pa1 = pa0 + 16 * D_DIM;
    const unsigned char* pb0 = fn8 + (size_t)(c0 + w * 32 + srow) * D_DIM + skoff;
    const unsigned char* pb1 = pb0 + 16 * D_DIM;

    f32x4 acc[4][4];
#pragma unroll
    for (int i = 0; i < 4; ++i)
#pragma unroll
        for (int j = 0; j < 4; ++j) acc[i][j] = (f32x4){0.f, 0.f, 0.f, 0.f};

    for (int kt = 0; kt < 16; ++kt) {
        __syncthreads();  // previous window's reads done before overwrite
        async_ld16(pa0, (void*)&As[(w * 2 + 0) * 1024]);
        async_ld16(pa1, (void*)&As[(w * 2 + 1) * 1024]);
        async_ld16(pb0, (void*)&Bs[(w * 2 + 0) * 1024]);
        async_ld16(pb1, (void*)&Bs[(w * 2 + 1) * 1024]);
        pa0 += 64; pa1 += 64; pb0 += 64; pb1 += 64;
        __syncthreads();  // drains vmcnt(0): staging visible

        long2_ af[4], bf[4];
#pragma unroll
        for (int i = 0; i < 4; ++i)
            af[i] = *(const long2_*)&As[(wr4 + i) * 1024 + lfo];
#pragma unroll
        for (int j = 0; j < 4; ++j)
            bf[j] = *(const long2_*)&Bs[(wc4 + j) * 1024 + lfo];
#pragma unroll
        for (int i = 0; i < 4; ++i)
#pragma unroll
            for (int j = 0; j < 4; ++j) {
                acc[i][j] = __builtin_amdgcn_mfma_f32_16x16x32_fp8_fp8(
                    af[i].x, bf[j].x, acc[i][j], 0, 0, 0);
                acc[i][j] = __builtin_amdgcn_mfma_f32_16x16x32_fp8_fp8(
                    af[i].y, bf[j].y, acc[i][j], 0, 0, 0);
            }
    }

    // epilogue: e = exp(sim - M); rows-in-I sums + (I<J) cols-in-J sums.
    float cs[4] = {0.f, 0.f, 0.f, 0.f};   // per-j column partial sums
#pragma unroll
    for (int i = 0; i < 4; ++i) {
        const int growb = r0 + wr + i * 16 + q * 4;
#pragma unroll
        for (int r = 0; r < 4; ++r) {
            const int grow = growb + r;
            float s = 0.f;
#pragma unroll
            for (int j = 0; j < 4; ++j) {
                const int gcol = c0 + wc + j * 16 + c16;
                float sim = acc[i][j][r] * INV_T;
                float e = __expf(sim - INV_T);
                if (isdiag && grow == gcol) e = 0.f;   // diagonal mask
                if (haspair && gcol == grow + HALF_N) {
                    __hip_atomic_store(&s_target[grow], sim, __ATOMIC_RELAXED,
                                       __HIP_MEMORY_SCOPE_AGENT);
                    __hip_atomic_store(&s_target[gcol], sim, __ATOMIC_RELAXED,
                                       __HIP_MEMORY_SCOPE_AGENT);
                }
                s += e;
                cs[j] += e;
            }
            // row path: reduce over the 16 col-lanes of the quad
            s += __shfl_xor(s, 1);
            s += __shfl_xor(s, 2);
            s += __shfl_xor(s, 4);
            s += __shfl_xor(s, 8);
            if (c16 == 0) atomicAdd(&row_sum[grow], s);
        }
    }
    if (!isdiag) {
        // col path: reduce each cs[j] across the 4 quads, one atomic/column
#pragma unroll
        for (int j = 0; j < 4; ++j) {
            float s = cs[j];
            s += __shfl_xor(s, 16);
            s += __shfl_xor(s, 32);
            if (q == 0) atomicAdd(&row_sum[c0 + wc + j * 16 + c16], s);
        }
    }

    // ---- fence-free fused loss tail, 8-way parallel ----
    __syncthreads();   // all waves' vmem drained (compiler emits vmcnt(0) here)
    __shared__ unsigned int my_ord;
    if (tid == 0)
        my_ord = __hip_atomic_fetch_add(done_cnt, 1u, __ATOMIC_RELAXED,
                                        __HIP_MEMORY_SCOPE_AGENT);
    __syncthreads();
    const unsigned int ord = my_ord;
    if (ord >= N_TILES - N_RED) {
        // wait until ALL 2080 blocks have signalled (their sums are in).
        if (tid == 0) {
            while (__hip_atomic_load(done_cnt, __ATOMIC_RELAXED,
                                     __HIP_MEMORY_SCOPE_AGENT) < N_TILES)
                __builtin_amdgcn_s_sleep(1);
        }
        __syncthreads();
        const int slice = (int)(ord - (N_TILES - N_RED));   // 0..7
        const int base_row = slice * (N_ROWS / N_RED) + tid * 4;
        float rv[4], sv[4];
#pragma unroll
        for (int u = 0; u < 4; ++u) {
            rv[u] = __hip_atomic_load(&row_sum[base_row + u], __ATOMIC_RELAXED,
                                      __HIP_MEMORY_SCOPE_AGENT);
            sv[u] = __hip_atomic_load(&s_target[base_row + u], __ATOMIC_RELAXED,
                                      __HIP_MEMORY_SCOPE_AGENT);
        }
        float local = 0.f;
#pragma unroll
        for (int u = 0; u < 4; ++u)
            local += __logf(rv[u]) - sv[u];
#pragma unroll
        for (int off = 32; off; off >>= 1) local += __shfl_xor(local, off);
        __shared__ float part[4];
        if ((tid & 63) == 0) part[tid >> 6] = local;
        __syncthreads();
        if (tid == 0) {
            float bsum = part[0] + part[1] + part[2] + part[3];
            __hip_atomic_fetch_add(loss_acc, bsum, __ATOMIC_RELAXED,
                                   __HIP_MEMORY_SCOPE_AGENT);
            unsigned int f = __hip_atomic_fetch_add(fin_cnt, 1u, __ATOMIC_ACQ_REL,
                                                    __HIP_MEMORY_SCOPE_AGENT);
            if (f == N_RED - 1) {
                float accv = __hip_atomic_load(loss_acc, __ATOMIC_RELAXED,
                                               __HIP_MEMORY_SCOPE_AGENT);
                out[0] = INV_T + accv * (1.0f / N_ROWS);
            }
        }
    }
}

// ---------------------------------------------------------------------------
extern "C" void kernel_launch(void* const* d_in, const int* in_sizes, int n_in,
                              void* d_out, int out_size, void* d_ws, size_t ws_size,
                              hipStream_t stream) {
    const float* feat = (const float*)d_in[0];
    float* out = (float*)d_out;
    char* ws = (char*)d_ws;

    unsigned char* fn8 = (unsigned char*)ws;                  // 8192*1024 fp8 = 8 MiB
    size_t off = (size_t)N_ROWS * D_DIM;
    float* row_sum = (float*)(ws + off);   off += N_ROWS * sizeof(float);
    float* s_target = (float*)(ws + off);  off += N_ROWS * sizeof(float);
    unsigned int* done_cnt = (unsigned int*)(ws + off);  off += sizeof(unsigned int);
    unsigned int* fin_cnt = (unsigned int*)(ws + off);   off += sizeof(unsigned int);
    float* loss_acc = (float*)(ws + off);

    norm_kernel<<<N_ROWS / 4, 256, 0, stream>>>(feat, fn8, row_sum, done_cnt, fin_cnt, loss_acc);
    simgemm_kernel<<<N_TILES, 256, 0, stream>>>(fn8, row_sum, s_target, done_cnt, fin_cnt, loss_acc, out);
}